// Round 1
// baseline (93.960 us; speedup 1.0000x reference)
//
#include <hip/hip_runtime.h>
#include <math.h>

// QuanvLayer1D collapsed form:
//   e_j(window) = t^T S_j t,  t_b = prod_k (b_k ? sin(x_k/2) : cos(x_k/2))
//   S_j[b][b'] = sum_a sign_j(a) Re( conj(q_b[a]) q_b'[a] ),  q_b = U3 * G^b * U0 |0>
// State layout per wave (64 lanes): amplitude a (8 bits) = r*64 + lane,
// qubit j <-> bit (7-j):  qubit0 -> reg bit1, qubit1 -> reg bit0,
// qubits 2..7 -> lane masks 32,16,8,4,2,1.

#define DEV __device__ __forceinline__

#define NQ 8
#define LOUT 511
#define LIN 512
#define BS 32

DEV float sx(float v, int m) { return __shfl_xor(v, m, 64); }

// ---------- single-qubit rotations ----------
template<int J>
DEV void rot_rx(float (&re)[4], float (&im)[4], float c, float s) {
    if constexpr (J == 0) {            // pairs (0,2),(1,3)
        float r0=re[0], i0=im[0], r2=re[2], i2=im[2];
        re[0]=c*r0+s*i2; im[0]=c*i0-s*r2; re[2]=c*r2+s*i0; im[2]=c*i2-s*r0;
        float r1=re[1], i1=im[1], r3=re[3], i3=im[3];
        re[1]=c*r1+s*i3; im[1]=c*i1-s*r3; re[3]=c*r3+s*i1; im[3]=c*i3-s*r1;
    } else if constexpr (J == 1) {     // pairs (0,1),(2,3)
        float r0=re[0], i0=im[0], r1=re[1], i1=im[1];
        re[0]=c*r0+s*i1; im[0]=c*i0-s*r1; re[1]=c*r1+s*i0; im[1]=c*i1-s*r0;
        float r2=re[2], i2=im[2], r3=re[3], i3=im[3];
        re[2]=c*r2+s*i3; im[2]=c*i2-s*r3; re[3]=c*r3+s*i2; im[3]=c*i3-s*r2;
    } else {
        constexpr int m = 1 << (7 - J);
        #pragma unroll
        for (int r = 0; r < 4; ++r) {
            float pre = sx(re[r], m), pim = sx(im[r], m);
            re[r] = c*re[r] + s*pim;
            im[r] = c*im[r] - s*pre;
        }
    }
}

template<int J>
DEV void rot_ry(float (&re)[4], float (&im)[4], float c, float s, int lane) {
    if constexpr (J == 0) {            // new_lo = c*lo - s*hi ; new_hi = s*lo + c*hi
        float r0=re[0], i0=im[0], r2=re[2], i2=im[2];
        re[0]=c*r0-s*r2; im[0]=c*i0-s*i2; re[2]=s*r0+c*r2; im[2]=s*i0+c*i2;
        float r1=re[1], i1=im[1], r3=re[3], i3=im[3];
        re[1]=c*r1-s*r3; im[1]=c*i1-s*i3; re[3]=s*r1+c*r3; im[3]=s*i1+c*i3;
    } else if constexpr (J == 1) {
        float r0=re[0], i0=im[0], r1=re[1], i1=im[1];
        re[0]=c*r0-s*r1; im[0]=c*i0-s*i1; re[1]=s*r0+c*r1; im[1]=s*i0+c*i1;
        float r2=re[2], i2=im[2], r3=re[3], i3=im[3];
        re[2]=c*r2-s*r3; im[2]=c*i2-s*i3; re[3]=s*r2+c*r3; im[3]=s*i2+c*i3;
    } else {
        constexpr int m = 1 << (7 - J);
        float sg = (lane & m) ? s : -s;
        #pragma unroll
        for (int r = 0; r < 4; ++r) {
            float pre = sx(re[r], m), pim = sx(im[r], m);
            re[r] = c*re[r] + sg*pre;
            im[r] = c*im[r] + sg*pim;
        }
    }
}

template<int J>
DEV void rot_rz(float (&re)[4], float (&im)[4], float c, float s, int lane) {
    if constexpr (J == 0) {            // bit0: *(c-is) for r0,r1 ; bit1: *(c+is) for r2,r3
        float t;
        t=re[0]; re[0]=c*t+s*im[0]; im[0]=c*im[0]-s*t;
        t=re[1]; re[1]=c*t+s*im[1]; im[1]=c*im[1]-s*t;
        t=re[2]; re[2]=c*t-s*im[2]; im[2]=c*im[2]+s*t;
        t=re[3]; re[3]=c*t-s*im[3]; im[3]=c*im[3]+s*t;
    } else if constexpr (J == 1) {     // bit0: r0,r2 ; bit1: r1,r3
        float t;
        t=re[0]; re[0]=c*t+s*im[0]; im[0]=c*im[0]-s*t;
        t=re[2]; re[2]=c*t+s*im[2]; im[2]=c*im[2]-s*t;
        t=re[1]; re[1]=c*t-s*im[1]; im[1]=c*im[1]+s*t;
        t=re[3]; re[3]=c*t-s*im[3]; im[3]=c*im[3]+s*t;
    } else {
        constexpr int m = 1 << (7 - J);
        float sg = (lane & m) ? -s : s;
        #pragma unroll
        for (int r = 0; r < 4; ++r) {
            float t = re[r];
            re[r] = c*t + sg*im[r];
            im[r] = c*im[r] - sg*t;
        }
    }
}

// ---------- CNOT for wire J: (c,t) = (J, J+1) for J<7, (0,7) for J==7 ----------
template<int J>
DEV void cnot_w(float (&re)[4], float (&im)[4], int lane) {
    if constexpr (J == 0) {            // ctrl reg bit1, tgt reg bit0: swap r2<->r3
        float t;
        t=re[2]; re[2]=re[3]; re[3]=t;
        t=im[2]; im[2]=im[3]; im[3]=t;
    } else if constexpr (J == 1) {     // ctrl reg bit0 (r1,r3), tgt lane 32: full swap
        re[1]=sx(re[1],32); im[1]=sx(im[1],32);
        re[3]=sx(re[3],32); im[3]=sx(im[3],32);
    } else if constexpr (J == 7) {     // CNOT(0,7): ctrl reg bit1 (r2,r3), tgt lane 1
        re[2]=sx(re[2],1); im[2]=sx(im[2],1);
        re[3]=sx(re[3],1); im[3]=sx(im[3],1);
    } else {                           // ctrl lane 1<<(7-J), tgt lane 1<<(6-J)
        constexpr int mc = 1 << (7 - J);
        constexpr int mt = 1 << (6 - J);
        bool ctrl = (lane & mc) != 0;
        #pragma unroll
        for (int r = 0; r < 4; ++r) {
            float pre = sx(re[r], mt), pim = sx(im[r], mt);
            re[r] = ctrl ? pre : re[r];
            im[r] = ctrl ? pim : im[r];
        }
    }
}

template<int J>
DEV void wire(float (&re)[4], float (&im)[4], float ang, int lane) {
    float s, c;
    sincosf(0.5f*ang, &s, &c);
    rot_rx<J>(re, im, c, s);
    cnot_w<J>(re, im, lane);
    rot_ry<J>(re, im, c, s, lane);
    cnot_w<J>(re, im, lane);
    rot_rz<J>(re, im, c, s, lane);
}

DEV void ansatz(float (&re)[4], float (&im)[4], const float* w, int lane) {
    wire<0>(re, im, w[0], lane);
    wire<1>(re, im, w[1], lane);
    wire<2>(re, im, w[2], lane);
    wire<3>(re, im, w[3], lane);
    wire<4>(re, im, w[4], lane);
    wire<5>(re, im, w[5], lane);
    wire<6>(re, im, w[6], lane);
    wire<7>(re, im, w[7], lane);
}

// ---------- kernel A1: q_b = ansatz3(ansatz2(ansatz1( G^b ansatz0|0> ))) ----------
__global__ __launch_bounds__(64) void kA1(const float* __restrict__ wts,
                                          float2* __restrict__ q) {
    int lane = threadIdx.x;
    int b = blockIdx.x;                // 0..15
    float re[4] = {0.f,0.f,0.f,0.f}, im[4] = {0.f,0.f,0.f,0.f};
    if (lane == 0) re[0] = 1.0f;
    ansatz(re, im, wts, lane);
    // apply G on qubit k for each set bit k of b.  G: new_lo = -hi, new_hi = lo.
    if (b & 1) {                       // qubit0: pairs (0,2),(1,3)
        float t;
        t=re[0]; re[0]=-re[2]; re[2]=t;  t=im[0]; im[0]=-im[2]; im[2]=t;
        t=re[1]; re[1]=-re[3]; re[3]=t;  t=im[1]; im[1]=-im[3]; im[3]=t;
    }
    if (b & 2) {                       // qubit1: pairs (0,1),(2,3)
        float t;
        t=re[0]; re[0]=-re[1]; re[1]=t;  t=im[0]; im[0]=-im[1]; im[1]=t;
        t=re[2]; re[2]=-re[3]; re[3]=t;  t=im[2]; im[2]=-im[3]; im[3]=t;
    }
    if (b & 4) {                       // qubit2: lane mask 32
        bool hi = (lane & 32) != 0;
        #pragma unroll
        for (int r = 0; r < 4; ++r) {
            float pre = sx(re[r],32), pim = sx(im[r],32);
            re[r] = hi ? pre : -pre;
            im[r] = hi ? pim : -pim;
        }
    }
    if (b & 8) {                       // qubit3: lane mask 16
        bool hi = (lane & 16) != 0;
        #pragma unroll
        for (int r = 0; r < 4; ++r) {
            float pre = sx(re[r],16), pim = sx(im[r],16);
            re[r] = hi ? pre : -pre;
            im[r] = hi ? pim : -pim;
        }
    }
    ansatz(re, im, wts + 8,  lane);
    ansatz(re, im, wts + 16, lane);
    ansatz(re, im, wts + 24, lane);
    #pragma unroll
    for (int r = 0; r < 4; ++r)
        q[b*256 + r*64 + lane] = make_float2(re[r], im[r]);
}

// ---------- kernel A2: S_j[b][bp] = sum_a sign_j(a) Re(conj(q_b) q_bp) ----------
__global__ __launch_bounds__(64) void kA2(const float2* __restrict__ q,
                                          float* __restrict__ S) {
    int lane = threadIdx.x;
    int b  = blockIdx.x >> 4;
    int bp = blockIdx.x & 15;
    float pp[4];
    #pragma unroll
    for (int rr = 0; rr < 4; ++rr) {
        float2 x = q[b*256  + rr*64 + lane];
        float2 y = q[bp*256 + rr*64 + lane];
        pp[rr] = x.x*y.x + x.y*y.y;
    }
    float acc[8];
    acc[0] = (pp[0]+pp[1]) - (pp[2]+pp[3]);   // qubit0: reg bit1
    acc[1] = (pp[0]+pp[2]) - (pp[1]+pp[3]);   // qubit1: reg bit0
    float tot = pp[0]+pp[1]+pp[2]+pp[3];
    acc[2] = (lane & 32) ? -tot : tot;
    acc[3] = (lane & 16) ? -tot : tot;
    acc[4] = (lane &  8) ? -tot : tot;
    acc[5] = (lane &  4) ? -tot : tot;
    acc[6] = (lane &  2) ? -tot : tot;
    acc[7] = (lane &  1) ? -tot : tot;
    #pragma unroll
    for (int j = 0; j < 8; ++j) {
        #pragma unroll
        for (int m = 1; m <= 32; m <<= 1)
            acc[j] += sx(acc[j], m);
    }
    if (lane == 0) {
        #pragma unroll
        for (int j = 0; j < 8; ++j)
            S[j*256 + b*16 + bp] = acc[j];
    }
}

// ---------- kernel B: per-window t, e_j = t^T S_j t ----------
__global__ __launch_bounds__(256) void kB(const float* __restrict__ vec,
                                          const float* __restrict__ S,
                                          float* __restrict__ out) {
    __shared__ float Sl[2048];
    for (int i = threadIdx.x; i < 2048; i += 256) Sl[i] = S[i];
    __syncthreads();
    int o   = blockIdx.x * 256 + threadIdx.x;
    int bat = blockIdx.y;
    if (o >= LOUT) return;
    float cs[4], sn[4];
    #pragma unroll
    for (int k = 0; k < 4; ++k) {
        int p = o + k;                 // padded index 0..513
        float x = (p >= 1 && p <= LIN) ? vec[bat*LIN + p - 1] : 0.f;
        sincosf(0.5f*x, &sn[k], &cs[k]);
    }
    float t[16];
    #pragma unroll
    for (int i = 0; i < 16; ++i)
        t[i] = ((i&1)?sn[0]:cs[0]) * ((i&2)?sn[1]:cs[1])
             * ((i&4)?sn[2]:cs[2]) * ((i&8)?sn[3]:cs[3]);
    for (int j = 0; j < 8; ++j) {
        float e = 0.f;
        #pragma unroll
        for (int b = 0; b < 16; ++b) {
            float u = 0.f;
            #pragma unroll
            for (int bp = 0; bp < 16; ++bp)
                u += Sl[j*256 + b*16 + bp] * t[bp];
            e += t[b] * u;
        }
        out[(bat*NQ + j)*LOUT + o] = e;
    }
}

extern "C" void kernel_launch(void* const* d_in, const int* in_sizes, int n_in,
                              void* d_out, int out_size, void* d_ws, size_t ws_size,
                              hipStream_t stream) {
    const float* vec = (const float*)d_in[0];   // (32,1,512) f32
    const float* wts = (const float*)d_in[1];   // (4,8) f32
    float* out = (float*)d_out;                 // (32,8,511) f32
    float2* q  = (float2*)d_ws;                 // 16*256 complex = 32 KB
    float*  S  = (float*)d_ws + 8192;           // 8*16*16 f32 = 8 KB
    kA1<<<16, 64, 0, stream>>>(wts, q);
    kA2<<<256, 64, 0, stream>>>(q, S);
    kB<<<dim3(2, BS), 256, 0, stream>>>(vec, S, out);
}